// Round 2
// baseline (8408.466 us; speedup 1.0000x reference)
//
#include <hip/hip_runtime.h>
#include <hip/hip_bf16.h>
#include <stdint.h>

// Problem dims
#define NB   128
#define NT   1024
#define NV   32000
#define NE   512
#define NH   512
#define NO   5
#define N4H  2048
#define CT   128            // timesteps per chunk
#define NCHUNK (NT / CT)    // 8

typedef __attribute__((ext_vector_type(8))) short short8;   // 8 bf16 = 4 VGPR
typedef __attribute__((ext_vector_type(4))) float f32x4;    // MFMA acc

__device__ __forceinline__ float bf2f(unsigned short u){
  union { unsigned int i; float f; } x; x.i = ((unsigned int)u) << 16; return x.f;
}
__device__ __forceinline__ unsigned short f2bf(float f){
  union { __hip_bfloat16 h; unsigned short u; } x;
  x.h = __float2bfloat16(f);   // RNE
  return x.u;
}
__device__ __forceinline__ float sigm_(float x){ return 1.f / (1.f + __expf(-x)); }
__device__ __forceinline__ float tanh_(float x){
  x = fminf(fmaxf(x, -20.f), 20.f);
  float e = __expf(2.f * x);
  return (e - 1.f) / (e + 1.f);
}
__device__ __forceinline__ void gl_lds16(const void* g, void* l){
  __builtin_amdgcn_global_load_lds((const __attribute__((address_space(1))) unsigned int*)g,
                                   (__attribute__((address_space(3))) unsigned int*)l, 16, 0, 0);
}

// ---------------- K0: embed fp32 -> bf16 ----------------
__global__ void k_cvt_embed(const float* __restrict__ e, unsigned short* __restrict__ o, long n){
  long i = ((long)blockIdx.x * blockDim.x + threadIdx.x) * 4;
  long stride = (long)gridDim.x * blockDim.x * 4;
  for (; i < n; i += stride){
    float4 v = *(const float4*)(e + i);
    ushort4 r;
    r.x = f2bf(v.x); r.y = f2bf(v.y); r.z = f2bf(v.z); r.w = f2bf(v.w);
    *(ushort4*)(o + i) = r;
  }
}

// ---------------- K1: build permuted bf16 weight panels ----------------
// Permuted col space: colP = (j>>4)*64 + gate*16 + (j&15), gate order f,i,o,c.
// WhT[colP][k] = W[k][g*512+j]        (h rows 0..511)
// WxT[colP][k] = W[512+k][g*512+j]    (x rows 512..1023)
__global__ void k_prep_w(const float* __restrict__ wf, const float* __restrict__ wi,
                         const float* __restrict__ wo, const float* __restrict__ wc,
                         const float* __restrict__ bfp, const float* __restrict__ bip,
                         const float* __restrict__ bop, const float* __restrict__ bcp,
                         unsigned short* __restrict__ WhT, unsigned short* __restrict__ WxT,
                         float* __restrict__ biasP){
  int colP = blockIdx.x;                 // 0..2047
  int blk = colP >> 6, rem = colP & 63;
  int g = rem >> 4, jl = rem & 15;
  int j = blk * 16 + jl;
  const float* w = (g == 0) ? wf : (g == 1) ? wi : (g == 2) ? wo : wc;
  const float* bb = (g == 0) ? bfp : (g == 1) ? bip : (g == 2) ? bop : bcp;
  for (int k = threadIdx.x; k < 512; k += blockDim.x){
    WhT[(long)colP * 512 + k] = f2bf(w[(long)k * 512 + j]);
    WxT[(long)colP * 512 + k] = f2bf(w[(long)(512 + k) * 512 + j]);
  }
  if (threadIdx.x == 0) biasP[colP] = bb[j];
}

// ---------------- K2: input projection GEMM for one time-chunk ----------------
// Chunk-local A rows m = b*CT + tl  (tl = t - c*CT).  B = WxT (B^T layout [N][K]).
// C -> xz[m][colP] bf16, +biasP
__launch_bounds__(256, 2)
__global__ void k_xproj(const int* __restrict__ tok, const unsigned short* __restrict__ embT,
                        const unsigned short* __restrict__ WxT, const float* __restrict__ biasP,
                        unsigned short* __restrict__ xz, int c){
  __shared__ unsigned short S[16384];           // 32 KB: A(16K) + B(16K), reused as C-tile
  unsigned short* Ash = S;
  unsigned short* Bsh = S + 8192;
  int bx = blockIdx.x;
  int tn = bx & 15, tm = bx >> 4;               // 16 n-tiles, 128 m-tiles
  int m0 = tm * 128, n0 = tn * 128;
  int tid = threadIdx.x, w = tid >> 6, l = tid & 63;

  long srcA[4], srcB[4];
  #pragma unroll
  for (int i = 0; i < 4; i++){
    int rr = 32 * w + 8 * i + (l >> 3);
    int r_glob = m0 + rr;                       // chunk-local row
    int b  = r_glob >> 7;                       // / CT
    int tl = r_glob & (CT - 1);
    int t = tok[b * NT + c * CT + tl];
    srcA[i] = (long)t * 512 + (l & 7) * 8;      // element offsets (ushort)
    srcB[i] = (long)(n0 + rr) * 512 + (l & 7) * 8;
  }
  f32x4 acc[4][4];
  f32x4 z4 = {0.f, 0.f, 0.f, 0.f};
  #pragma unroll
  for (int mt = 0; mt < 4; mt++)
    #pragma unroll
    for (int nt = 0; nt < 4; nt++) acc[mt][nt] = z4;

  int wm = w >> 1, wn = w & 1;
  for (int kt = 0; kt < 8; kt++){
    #pragma unroll
    for (int i = 0; i < 4; i++){
      gl_lds16(embT + srcA[i] + kt * 64, Ash + (32 * w + 8 * i) * 64);
      gl_lds16(WxT  + srcB[i] + kt * 64, Bsh + (32 * w + 8 * i) * 64);
    }
    __syncthreads();
    #pragma unroll
    for (int kk = 0; kk < 2; kk++){
      short8 a[4], b[4];
      #pragma unroll
      for (int mt = 0; mt < 4; mt++)
        a[mt] = *(const short8*)(Ash + (64 * wm + 16 * mt + (l & 15)) * 64 + kk * 32 + (l >> 4) * 8);
      #pragma unroll
      for (int nt = 0; nt < 4; nt++)
        b[nt] = *(const short8*)(Bsh + (64 * wn + 16 * nt + (l & 15)) * 64 + kk * 32 + (l >> 4) * 8);
      #pragma unroll
      for (int mt = 0; mt < 4; mt++)
        #pragma unroll
        for (int nt = 0; nt < 4; nt++)
          acc[mt][nt] = __builtin_amdgcn_mfma_f32_16x16x32_bf16(a[mt], b[nt], acc[mt][nt], 0, 0, 0);
    }
    __syncthreads();
  }
  // epilogue: acc -> LDS C-tile (bf16, +bias), then coalesced copy-out
  #pragma unroll
  for (int mt = 0; mt < 4; mt++)
    #pragma unroll
    for (int nt = 0; nt < 4; nt++)
      #pragma unroll
      for (int r = 0; r < 4; r++){
        int mm = 64 * wm + 16 * mt + 4 * (l >> 4) + r;
        int nn = 64 * wn + 16 * nt + (l & 15);
        float z = acc[mt][nt][r] + biasP[n0 + nn];
        S[mm * 128 + nn] = f2bf(z);
      }
  __syncthreads();
  #pragma unroll
  for (int it = 0; it < 8; it++){
    int i = it * 256 + tid;                 // 0..2047
    int row = i >> 4, ch = i & 15;
    *reinterpret_cast<uint4*>(xz + (long)(m0 + row) * 2048 + n0 + ch * 8) =
        *reinterpret_cast<const uint4*>(S + row * 128 + ch * 8);
  }
}

// ---------------- K3: recurrent LSTM, one time-chunk (64 blocks, plain launch) ----------------
// 8 groups x (8 wg x 4 waves). Wave owns 16 dims x 4 gates; W_h frags stationary in VGPRs.
// Counter cnt[g] is monotone in GLOBAL t across chunk launches.
__launch_bounds__(256, 1)
__global__ void k_lstm(const int* __restrict__ seqlen,
                       const unsigned short* __restrict__ WhT,
                       const unsigned short* __restrict__ xz,   // chunk-local [128][CT][2048]
                       unsigned short* __restrict__ hbuf,       // [2][128][512] bf16
                       float* __restrict__ hfin,                // [128][512] f32
                       int* __restrict__ cnt,                   // per-group counters, stride 16 ints
                       float* __restrict__ cbuf,                // [128][512] f32 c-state
                       int c){
  int bid = blockIdx.x;
  int g = bid & 7, member = bid >> 3;
  int tid = threadIdx.x, wv = tid >> 6, l = tid & 63;
  int wglob = member * 4 + wv;            // 0..31
  int bbase = g * 16;
  int lm = l & 15, lh = l >> 4;
  int blocal0 = 4 * lh;

  // seq lens for this lane's 4 rows + group max
  int len[4];
  #pragma unroll
  for (int r = 0; r < 4; r++) len[r] = seqlen[bbase + blocal0 + r];
  int ml = max(max(len[0], len[1]), max(len[2], len[3]));
  #pragma unroll
  for (int off = 32; off; off >>= 1) ml = max(ml, __shfl_xor(ml, off));
  int maxlen = ml;

  int tstart = c * CT;
  int tend = min(tstart + CT, maxlen);

  // stationary W_h fragments: 4 gates x 16 k-steps
  short8 Bf[4][16];
  #pragma unroll
  for (int gg = 0; gg < 4; gg++){
    long cbase = (long)(wglob * 64 + gg * 16 + lm) * 512 + lh * 8;
    #pragma unroll
    for (int kk = 0; kk < 16; kk++)
      Bf[gg][kk] = *(const short8*)(WhT + cbase + kk * 32);
  }

  long xzb[4];
  long cidx[4];
  #pragma unroll
  for (int r = 0; r < 4; r++){
    int b = bbase + blocal0 + r;
    xzb[r]  = (long)b * (CT * 2048) + wglob * 64 + lm;   // + tl*2048 + gg*16
    cidx[4 > r ? r : 0] = (long)b * 512 + wglob * 16 + lm;
  }

  // c-state: zeros at t=0, else restore from cbuf
  float cst[4];
  #pragma unroll
  for (int r = 0; r < 4; r++)
    cst[r] = (c == 0) ? 0.f : cbuf[cidx[r]];

  const unsigned long long* hb64 = (const unsigned long long*)hbuf;
  f32x4 zero4 = {0.f, 0.f, 0.f, 0.f};

  for (int t = tstart; t < tend; t++){
    int tl = t - tstart;
    // issue xz[t] loads early (no cross-wg dependency; latency hides under spin+MFMA)
    unsigned short xv[16];
    #pragma unroll
    for (int gg = 0; gg < 4; gg++)
      #pragma unroll
      for (int r = 0; r < 4; r++)
        xv[gg * 4 + r] = xz[xzb[r] + (long)tl * 2048 + gg * 16];

    f32x4 acc[4] = {zero4, zero4, zero4, zero4};
    if (t > 0){
      if (tid == 0){
        while (__hip_atomic_load(&cnt[g * 16], __ATOMIC_ACQUIRE, __HIP_MEMORY_SCOPE_AGENT) < 8 * t)
          __builtin_amdgcn_s_sleep(1);
      }
      __syncthreads();
      long au = (((long)((t - 1) & 1)) * 65536 + (long)(bbase + lm) * 512 + lh * 8) >> 2;
      short8 Af[16];
      #pragma unroll
      for (int kk = 0; kk < 16; kk++){
        unsigned long long lo = __hip_atomic_load(hb64 + au + kk * 8,     __ATOMIC_RELAXED, __HIP_MEMORY_SCOPE_AGENT);
        unsigned long long hi = __hip_atomic_load(hb64 + au + kk * 8 + 1, __ATOMIC_RELAXED, __HIP_MEMORY_SCOPE_AGENT);
        struct P { unsigned long long a, b; } p{lo, hi};
        Af[kk] = __builtin_bit_cast(short8, p);
      }
      #pragma unroll
      for (int kk = 0; kk < 16; kk++)
        #pragma unroll
        for (int gg = 0; gg < 4; gg++)
          acc[gg] = __builtin_amdgcn_mfma_f32_16x16x32_bf16(Af[kk], Bf[gg][kk], acc[gg], 0, 0, 0);
    }
    // lane-local gates: lane holds all 4 gates of (b=bbase+4*lh+r, dim=wglob*16+lm)
    #pragma unroll
    for (int r = 0; r < 4; r++){
      float zf = acc[0][r] + bf2f(xv[0 * 4 + r]);
      float zi = acc[1][r] + bf2f(xv[1 * 4 + r]);
      float zo = acc[2][r] + bf2f(xv[2 * 4 + r]);
      float zc = acc[3][r] + bf2f(xv[3 * 4 + r]);
      float fg = sigm_(zf), ig = sigm_(zi), og = sigm_(zo);
      float ch = tanh_(zc);
      float cn = fg * cst[r] + ig * ch;
      cst[r] = cn;
      float hn = og * tanh_(cn);
      int b = bbase + blocal0 + r;
      unsigned short h16 = f2bf(hn);
      __hip_atomic_store(&hbuf[(long)(t & 1) * 65536 + (long)b * 512 + wglob * 16 + lm],
                         h16, __ATOMIC_RELAXED, __HIP_MEMORY_SCOPE_AGENT);
      if (t == len[r] - 1) hfin[cidx[r]] = hn;
    }
    __syncthreads();   // per-wave vmcnt(0) drain -> all h stores at coherent point
    if (tid == 0)
      __hip_atomic_fetch_add(&cnt[g * 16], 1, __ATOMIC_RELEASE, __HIP_MEMORY_SCOPE_AGENT);
  }

  // persist c-state for next chunk
  #pragma unroll
  for (int r = 0; r < 4; r++) cbuf[cidx[r]] = cst[r];
}

// ---------------- K4: final FC [128,512]@[512,5] fp32 ----------------
__global__ void k_fc(const float* __restrict__ hfin, const float* __restrict__ fcw,
                     const float* __restrict__ fcb, float* __restrict__ out){
  int b = blockIdx.x;
  int l = threadIdx.x;                     // 64 threads = 1 wave
  const float* h = hfin + (long)b * 512;
  float a[5] = {0.f, 0.f, 0.f, 0.f, 0.f};
  for (int k = l; k < 512; k += 64){
    float hv = h[k];
    #pragma unroll
    for (int o = 0; o < 5; o++) a[o] += hv * fcw[k * 5 + o];
  }
  #pragma unroll
  for (int o = 0; o < 5; o++){
    float v = a[o];
    #pragma unroll
    for (int off = 32; off; off >>= 1) v += __shfl_xor(v, off);
    if (l == 0) out[b * 5 + o] = v + fcb[o];
  }
}

extern "C" void kernel_launch(void* const* d_in, const int* in_sizes, int n_in,
                              void* d_out, int out_size, void* d_ws, size_t ws_size,
                              hipStream_t stream) {
  const int*   inputs = (const int*)  d_in[0];
  const int*   seqlen = (const int*)  d_in[1];
  const float* embed  = (const float*)d_in[2];
  const float* wf  = (const float*)d_in[3];
  const float* bfp = (const float*)d_in[4];
  const float* wi  = (const float*)d_in[5];
  const float* bip = (const float*)d_in[6];
  const float* wo  = (const float*)d_in[7];
  const float* bop = (const float*)d_in[8];
  const float* wc  = (const float*)d_in[9];
  const float* bcp = (const float*)d_in[10];
  const float* fcw = (const float*)d_in[11];
  const float* fcb = (const float*)d_in[12];
  float* out = (float*)d_out;

  // workspace layout (bytes)
  size_t SZ_XZ   = (size_t)NB * CT * N4H * 2;      // 64 MB (one time-chunk)
  size_t SZ_EMBT = (size_t)NV * NE * 2;            // 31.25 MB
  size_t SZ_W    = (size_t)N4H * 512 * 2;          // 2 MB
  size_t SZ_BIAS = (size_t)N4H * 4;                // 8 KB
  size_t SZ_HBUF = (size_t)2 * NB * NH * 2;        // 256 KB
  size_t SZ_F32B = (size_t)NB * NH * 4;            // 256 KB (cbuf / hfin)
  size_t need = SZ_XZ + SZ_EMBT + 2 * SZ_W + SZ_BIAS + SZ_HBUF + 2 * SZ_F32B + 512;
  if (ws_size < need){
    // diagnostic signature: zero output (reproduces round-0 absmax) instead of OOB writes
    hipMemsetAsync(d_out, 0, (size_t)out_size * 4, stream);
    return;
  }

  char* ws = (char*)d_ws;
  unsigned short* xz    = (unsigned short*)(ws);
  unsigned short* embT  = (unsigned short*)(ws + SZ_XZ);
  unsigned short* WxT   = (unsigned short*)(ws + SZ_XZ + SZ_EMBT);
  unsigned short* WhT   = (unsigned short*)(ws + SZ_XZ + SZ_EMBT + SZ_W);
  float*          biasP = (float*)        (ws + SZ_XZ + SZ_EMBT + 2 * SZ_W);
  unsigned short* hbuf  = (unsigned short*)(ws + SZ_XZ + SZ_EMBT + 2 * SZ_W + SZ_BIAS);
  float*          cbuf  = (float*)        (ws + SZ_XZ + SZ_EMBT + 2 * SZ_W + SZ_BIAS + SZ_HBUF);
  float*          hfin  = (float*)        (ws + SZ_XZ + SZ_EMBT + 2 * SZ_W + SZ_BIAS + SZ_HBUF + SZ_F32B);
  int*            cnt   = (int*)          (ws + SZ_XZ + SZ_EMBT + 2 * SZ_W + SZ_BIAS + SZ_HBUF + 2 * SZ_F32B);

  hipMemsetAsync(cnt, 0, 512, stream);
  k_cvt_embed<<<2048, 256, 0, stream>>>(embed, embT, (long)NV * NE);
  k_prep_w<<<2048, 256, 0, stream>>>(wf, wi, wo, wc, bfp, bip, bop, bcp, WhT, WxT, biasP);

  for (int c = 0; c < NCHUNK; c++){
    k_xproj<<<2048, 256, 0, stream>>>(inputs, embT, WxT, biasP, xz, c);
    k_lstm<<<64, 256, 0, stream>>>(seqlen, WhT, xz, hbuf, hfin, cnt, cbuf, c);
  }
  k_fc<<<128, 64, 0, stream>>>(hfin, fcw, fcb, out);
}